// Round 1
// 141.062 us; speedup vs baseline: 1.0319x; 1.0319x over previous
//
#include <hip/hip_runtime.h>
#include <math.h>

#define H 64
#define W 64
#define C 128
#define NB 8
#define COUT 128
#define HWi 4096
#define NKC 36
#define PADu 40          // LDS row pitch in ushorts (80B = 5 superbanks, conflict-free b128)

typedef __attribute__((ext_vector_type(8))) short short8;
typedef __attribute__((ext_vector_type(8))) unsigned short ushort8;
typedef __attribute__((ext_vector_type(4))) unsigned short ushort4v;
typedef __attribute__((ext_vector_type(4))) float f32x4;

__device__ __forceinline__ unsigned short f2bf(float f){
    unsigned u = __float_as_uint(f);
    unsigned r = (u + 0x7FFFu + ((u >> 16) & 1u)) >> 16;
    return (unsigned short)r;
}
__device__ __forceinline__ float bf2f(unsigned short u){
    return __uint_as_float(((unsigned)u) << 16);
}

// ---------- k_pre: fused x-transpose + weight prep + psum zero ----------
// blocks [0,528): x NCHW fp32 -> zero-padded NHWC bf16 [8][66][66][128]
//   XCD-affine: batch = bid & 7  (528 = 8 batches x 66 rows; bid%8 ~ XCD id)
//   so batch b's xTp slice (1.1 MB) is written into XCD b's L2, where
//   k_gemm27/k_gemm128 (same swizzle) will read it.
// blocks [528,1250): wAv swizzled [kc][q4][r128][j8], w27A [kc][m32][kk32], biasom, psum=0
__global__ void k_pre(const float* __restrict__ x, unsigned short* __restrict__ xTp,
                      const float* __restrict__ w_reg, const float* __restrict__ w_off,
                      const float* __restrict__ w_mod, const float* __restrict__ b_off,
                      const float* __restrict__ b_mod,
                      unsigned short* __restrict__ wAv, unsigned short* __restrict__ w27A,
                      float* __restrict__ biasom, float* __restrict__ psum){
    int tid = threadIdx.x;
    if (blockIdx.x >= 528){
        int i = (blockIdx.x - 528) * 256 + tid;
        if (i < 147456){
            int kc = i >> 12, rem = i & 4095;
            int q = rem >> 10, r = (rem >> 3) & 127, j = rem & 7;
            int kk = kc * 32 + q * 8 + j, k = kk >> 7, c = kk & 127;
            wAv[i] = f2bf(w_reg[r * 1152 + c * 9 + k]);
        } else if (i < 147456 + 36864){
            int j2 = i - 147456;
            int kc = j2 >> 10, rem = j2 & 1023, m = rem >> 5, kkl = rem & 31;
            int kk = kc * 32 + kkl, k = kk >> 7, c = kk & 127;
            float v = 0.f;
            if (m < 18) v = w_off[m * 1152 + c * 9 + k];
            else if (m < 27) v = w_mod[(m - 18) * 1152 + c * 9 + k];
            w27A[j2] = f2bf(v);
        } else if (i < 147456 + 36864 + 32){
            int m = i - 147456 - 36864;
            biasom[m] = (m < 18) ? b_off[m] : (m < 27 ? b_mod[m - 18] : 0.f);
        } else if (i < 147456 + 36864 + 32 + 256){
            psum[i - 147456 - 36864 - 32] = 0.f;
        }
        return;
    }
    int bidx = blockIdx.x;
    int b = bidx & 7, hp = bidx >> 3;       // XCD-affine: batch = bid%8
    unsigned short* row = xTp + (size_t)(b * 66 + hp) * 66 * 128;
    if (hp == 0 || hp == 65){
        ushort8 z = {0,0,0,0,0,0,0,0};
        for (int i = tid; i < 66 * 128 / 8; i += 256) ((ushort8*)row)[i] = z;
        return;
    }
    int h = hp - 1;
    __shared__ unsigned short s[64 * 136];
    int w = tid & 63, c0 = tid >> 6;
    for (int cc = 0; cc < 128; cc += 4){
        int c = cc + c0;
        s[w * 136 + c] = f2bf(x[(size_t)(b * 128 + c) * HWi + h * 64 + w]);
    }
    __syncthreads();
    if (tid < 32){
        ushort8 z = {0,0,0,0,0,0,0,0};
        int wp = (tid < 16) ? 0 : 65;
        int sg = tid & 15;
        *(ushort8*)(row + wp * 128 + sg * 8) = z;
    }
    for (int it = tid; it < 1024; it += 256){
        int w2 = it >> 4, sg = it & 15;
        *(ushort8*)(row + (w2 + 1) * 128 + sg * 8) = *(const ushort8*)(s + w2 * 136 + sg * 8);
    }
}

// ---------- k_gemm27: offset+mod conv, MFMA, padded LDS, pipelined ----------
__global__ __launch_bounds__(256) void k_gemm27(const unsigned short* __restrict__ xTp,
        const unsigned short* __restrict__ w27A, const float* __restrict__ biasom,
        unsigned short* __restrict__ OM){
    __shared__ unsigned short sA[2][32 * PADu];
    __shared__ unsigned short sB[2][64 * PADu];
    int tid = threadIdx.x;
    // XCD-affine swizzle: 512 blocks = 8 batches x 64 rows; pin batch (bid&7) to XCD (bid&7)
    int lb = (blockIdx.x & 7) * 64 + (blockIdx.x >> 3);
    int n0 = lb * 64;
    int b = n0 >> 12, h = (n0 >> 6) & 63;
    int wv = tid >> 6, lane = tid & 63, quad = lane >> 4, l16 = lane & 15;
    int nl = tid >> 2, sg = tid & 3;
    f32x4 acc0 = {0.f,0.f,0.f,0.f}, acc1 = {0.f,0.f,0.f,0.f};

    ushort8 rA, rB;
    auto loadNext = [&](int kcn){
        int k = kcn >> 2, cb = (kcn & 3) << 5;
        int ki = k / 3, kj = k - ki * 3;
        if (tid < 128) rA = *(const ushort8*)(w27A + kcn * 1024 + tid * 8);
        int rowi = (b * 66 + h + ki) * 66 + (nl + kj);
        rB = *(const ushort8*)(xTp + (size_t)rowi * 128 + cb + sg * 8);
    };
    loadNext(0);
    for (int kc = 0; kc < NKC; kc++){
        int p = kc & 1;
        if (tid < 128) *(ushort8*)(&sA[p][(tid >> 2) * PADu + (tid & 3) * 8]) = rA;
        *(ushort8*)(&sB[p][nl * PADu + sg * 8]) = rB;
        if (kc + 1 < NKC) loadNext(kc + 1);
        __syncthreads();
        short8 bfrag = *(const short8*)(&sB[p][(wv * 16 + l16) * PADu + quad * 8]);
        short8 a0 = *(const short8*)(&sA[p][l16 * PADu + quad * 8]);
        short8 a1 = *(const short8*)(&sA[p][(16 + l16) * PADu + quad * 8]);
        acc0 = __builtin_amdgcn_mfma_f32_16x16x32_bf16(a0, bfrag, acc0, 0, 0, 0);
        acc1 = __builtin_amdgcn_mfma_f32_16x16x32_bf16(a1, bfrag, acc1, 0, 0, 0);
    }
    int n = n0 + wv * 16 + l16;
    #pragma unroll
    for (int t = 0; t < 2; t++){
        f32x4 a = t ? acc1 : acc0;
        ushort4v o;
        #pragma unroll
        for (int r = 0; r < 4; r++){
            int oc = t * 16 + quad * 4 + r;
            float v = a[r] + biasom[oc];
            if (oc >= 18) v = 2.f / (1.f + expf(-v));
            o[r] = f2bf(v);
        }
        *(ushort4v*)(OM + n * 32 + t * 16 + quad * 4) = o;
    }
}

// ---------- k_gemm128: deformable conv, 512 thr, padded LDS, 1 barrier/kc ----------
__global__ __launch_bounds__(512, 4) void k_gemm128(const unsigned short* __restrict__ xTp,
        const unsigned short* __restrict__ OM, const unsigned short* __restrict__ wAv,
        const float* __restrict__ b_reg, unsigned short* __restrict__ ybf,
        float* __restrict__ psum){
    __shared__ char smem[49152];
    unsigned short* sA = (unsigned short*)smem;             // [2][128*40] = 20480 B
    unsigned short* sB = (unsigned short*)(smem + 20480);   // [2][64*40]  = 10240 B
    int*   s_a0 = (int*)(smem + 30720);                     // [4][576]    = 9216 B
    float* s_w0 = (float*)(smem + 39936);                   // [4][576]    = 9216 B

    int tid = threadIdx.x;
    // XCD-affine swizzle: 512 blocks = 8 batches x 64 rows. Dispatch maps
    // bid%8 -> XCD, so batch (bid&7) runs entirely on one XCD; its 1.1 MB
    // xTp slice then fits that XCD's 4 MB L2 -> gathers become L2 hits.
    int lb = (blockIdx.x & 7) * 64 + (blockIdx.x >> 3);
    int n0 = lb * 64;
    int b = n0 >> 12, h = (n0 >> 6) & 63;

    for (int idx = tid; idx < 576; idx += 512){
        int k = idx >> 6, px = idx & 63;
        int n = n0 + px;
        float dy = bf2f(OM[n * 32 + 2 * k]);
        float dx = bf2f(OM[n * 32 + 2 * k + 1]);
        float m  = bf2f(OM[n * 32 + 18 + k]);
        int ki = k / 3, kj = k - ki * 3;
        float py  = (float)(h - 1 + ki) + dy;
        float pxf = (float)(px - 1 + kj) + dx;
        float y0f = floorf(py), x0f = floorf(pxf);
        float ly = py - y0f, lx = pxf - x0f;
        int iy0 = (int)y0f, ix0 = (int)x0f;
        int cy0 = min(max(iy0 + 1, 0), 65), cy1 = min(max(iy0 + 2, 0), 65);
        int cx0 = min(max(ix0 + 1, 0), 65), cx1 = min(max(ix0 + 2, 0), 65);
        int rb = b * 66 * 66;
        s_a0[0 * 576 + idx] = ((rb + cy0 * 66) + cx0) * 128;
        s_a0[1 * 576 + idx] = ((rb + cy0 * 66) + cx1) * 128;
        s_a0[2 * 576 + idx] = ((rb + cy1 * 66) + cx0) * 128;
        s_a0[3 * 576 + idx] = ((rb + cy1 * 66) + cx1) * 128;
        s_w0[0 * 576 + idx] = (1.f - ly) * (1.f - lx) * m;
        s_w0[1 * 576 + idx] = (1.f - ly) * lx * m;
        s_w0[2 * 576 + idx] = ly * (1.f - lx) * m;
        s_w0[3 * 576 + idx] = ly * lx * m;
    }
    __syncthreads();

    int wv = tid >> 6, lane = tid & 63, quad = lane >> 4, l16 = lane & 15;
    int ocq = wv & 3, ng = wv >> 2;
    int rA = tid & 127, qA = tid >> 7;            // sA staging role
    int spx = (tid & 255) >> 2, scq = tid & 3;    // sampling role (tid<256)
    bool samp = (tid < 256);

    f32x4 acc00 = {0.f,0.f,0.f,0.f}, acc01 = {0.f,0.f,0.f,0.f};
    f32x4 acc10 = {0.f,0.f,0.f,0.f}, acc11 = {0.f,0.f,0.f,0.f};

    ushort8 rW, rc0, rc1, rc2, rc3;
    float w0 = 0.f, w1 = 0.f, w2 = 0.f, w3 = 0.f;

    auto loadNext = [&](int kcn){
        rW = *(const ushort8*)(wAv + kcn * 4096 + tid * 8);
        if (samp){
            int k = kcn >> 2, cb = (kcn & 3) << 5;
            int idx = k * 64 + spx;
            int co = cb + scq * 8;
            w0 = s_w0[0 * 576 + idx]; w1 = s_w0[1 * 576 + idx];
            w2 = s_w0[2 * 576 + idx]; w3 = s_w0[3 * 576 + idx];
            rc0 = *(const ushort8*)(xTp + s_a0[0 * 576 + idx] + co);
            rc1 = *(const ushort8*)(xTp + s_a0[1 * 576 + idx] + co);
            rc2 = *(const ushort8*)(xTp + s_a0[2 * 576 + idx] + co);
            rc3 = *(const ushort8*)(xTp + s_a0[3 * 576 + idx] + co);
        }
    };
    loadNext(0);
    for (int kc = 0; kc < NKC; kc++){
        int p = kc & 1;
        *(ushort8*)(sA + p * 5120 + rA * PADu + qA * 8) = rW;
        if (samp){
            ushort8 o;
            #pragma unroll
            for (int s = 0; s < 8; s++){
                float v = w0 * bf2f(rc0[s]) + w1 * bf2f(rc1[s])
                        + w2 * bf2f(rc2[s]) + w3 * bf2f(rc3[s]);
                o[s] = f2bf(v);
            }
            *(ushort8*)(sB + p * 2560 + spx * PADu + scq * 8) = o;
        }
        if (kc + 1 < NKC) loadNext(kc + 1);
        __syncthreads();
        const unsigned short* A = sA + p * 5120;
        const unsigned short* Bn = sB + p * 2560;
        short8 a0 = *(const short8*)(A + (ocq * 32 + l16) * PADu + quad * 8);
        short8 a1 = *(const short8*)(A + (ocq * 32 + 16 + l16) * PADu + quad * 8);
        short8 b0 = *(const short8*)(Bn + (ng * 32 + l16) * PADu + quad * 8);
        short8 b1 = *(const short8*)(Bn + (ng * 32 + 16 + l16) * PADu + quad * 8);
        acc00 = __builtin_amdgcn_mfma_f32_16x16x32_bf16(a0, b0, acc00, 0, 0, 0);
        acc01 = __builtin_amdgcn_mfma_f32_16x16x32_bf16(a0, b1, acc01, 0, 0, 0);
        acc10 = __builtin_amdgcn_mfma_f32_16x16x32_bf16(a1, b0, acc10, 0, 0, 0);
        acc11 = __builtin_amdgcn_mfma_f32_16x16x32_bf16(a1, b1, acc11, 0, 0, 0);
    }

    __syncthreads();
    float* ls = (float*)smem;   // [128][68] fp32 = 34816 B (overlaps tiles; done with them)
    int sp0 = h * 64;
    #pragma unroll
    for (int to = 0; to < 2; to++){
        #pragma unroll
        for (int tn = 0; tn < 2; tn++){
            f32x4 a = to ? (tn ? acc11 : acc10) : (tn ? acc01 : acc00);
            int nl = ng * 32 + tn * 16 + l16;
            #pragma unroll
            for (int r = 0; r < 4; r++){
                int oc = ocq * 32 + to * 16 + quad * 4 + r;
                float v = a[r] + b_reg[oc];
                ybf[(size_t)(b * 128 + oc) * HWi + sp0 + nl] = f2bf(v);
                ls[oc * 68 + nl] = v;
            }
        }
    }
    __syncthreads();
    if (tid < 128){
        int oc = tid;
        float s = 0.f, s2 = 0.f;
        #pragma unroll 8
        for (int nl = 0; nl < 64; nl++){
            float v = ls[oc * 68 + nl];
            s += v; s2 = fmaf(v, v, s2);
        }
        atomicAdd(&psum[oc], s);
        atomicAdd(&psum[128 + oc], s2);
    }
}

// ---------- k_apply: BN (stats inline from psum) + affine + relu -> fp32 ----------
__global__ void k_apply(const unsigned short* __restrict__ ybf, const float* __restrict__ psum,
                        const float* __restrict__ gamma, const float* __restrict__ beta,
                        float* __restrict__ out){
    // XCD-affine swizzle: 2048 blocks = 8 batches x 256; read ybf from the XCD
    // whose k_gemm128 blocks (same batch) wrote it.
    int lb = ((int)blockIdx.x & 7) * 256 + ((int)blockIdx.x >> 3);
    int e8 = (lb * 256 + (int)threadIdx.x) * 8;
    int c = (e8 >> 12) & 127;
    ushort8 u = *(const ushort8*)(ybf + e8);
    float s = psum[c], s2 = psum[128 + c];
    float mean = s * (1.f / 32768.f);
    float var  = s2 * (1.f / 32768.f) - mean * mean;
    float rs = rsqrtf(var + 1e-5f);
    float g = gamma[c] * rs;
    float bt = beta[c] - mean * g;
    float4 lo, hi;
    lo.x = fmaxf(fmaf(bf2f(u[0]), g, bt), 0.f);
    lo.y = fmaxf(fmaf(bf2f(u[1]), g, bt), 0.f);
    lo.z = fmaxf(fmaf(bf2f(u[2]), g, bt), 0.f);
    lo.w = fmaxf(fmaf(bf2f(u[3]), g, bt), 0.f);
    hi.x = fmaxf(fmaf(bf2f(u[4]), g, bt), 0.f);
    hi.y = fmaxf(fmaf(bf2f(u[5]), g, bt), 0.f);
    hi.z = fmaxf(fmaf(bf2f(u[6]), g, bt), 0.f);
    hi.w = fmaxf(fmaf(bf2f(u[7]), g, bt), 0.f);
    *(float4*)(out + e8)     = lo;
    *(float4*)(out + e8 + 4) = hi;
}

extern "C" void kernel_launch(void* const* d_in, const int* in_sizes, int n_in,
                              void* d_out, int out_size, void* d_ws, size_t ws_size,
                              hipStream_t stream){
    const float* x     = (const float*)d_in[0];
    const float* w_off = (const float*)d_in[1];
    const float* b_off = (const float*)d_in[2];
    const float* w_mod = (const float*)d_in[3];
    const float* b_mod = (const float*)d_in[4];
    const float* w_reg = (const float*)d_in[5];
    const float* b_reg = (const float*)d_in[6];
    const float* gamma = (const float*)d_in[7];
    const float* beta  = (const float*)d_in[8];

    char* wsb = (char*)d_ws;
    unsigned short* xTp   = (unsigned short*)(wsb);                    // 8,921,088 B
    unsigned short* OM    = (unsigned short*)(wsb + 8921088);          // 2,097,152 B
    unsigned short* ybf   = (unsigned short*)(wsb + 11018240);         // 8,388,608 B
    unsigned short* wAv   = (unsigned short*)(wsb + 19406848);         //   294,912 B
    unsigned short* w27A  = (unsigned short*)(wsb + 19701760);         //    73,728 B
    float*          biasom= (float*)(wsb + 19775488);                  //       128 B
    float*          psum  = (float*)(wsb + 19775616);                  //     1,024 B
    float* out = (float*)d_out;

    hipLaunchKernelGGL(k_pre,    dim3(1250), dim3(256), 0, stream, x, xTp, w_reg, w_off, w_mod, b_off, b_mod, wAv, w27A, biasom, psum);
    hipLaunchKernelGGL(k_gemm27, dim3(512),  dim3(256), 0, stream, xTp, w27A, biasom, OM);
    hipLaunchKernelGGL(k_gemm128,dim3(512),  dim3(512), 0, stream, xTp, OM, wAv, b_reg, ybf, psum);
    hipLaunchKernelGGL(k_apply,  dim3(2048), dim3(256), 0, stream, ybf, psum, gamma, beta, out);
}

// Round 3
// 137.147 us; speedup vs baseline: 1.0613x; 1.0285x over previous
//
#include <hip/hip_runtime.h>
#include <math.h>

#define H 64
#define W 64
#define C 128
#define NB 8
#define COUT 128
#define HWi 4096
#define NKC 36
#define PADu 40          // LDS row pitch in ushorts (80B = 5 superbanks, conflict-free b128)

typedef __attribute__((ext_vector_type(8))) short short8;
typedef __attribute__((ext_vector_type(8))) unsigned short ushort8;
typedef __attribute__((ext_vector_type(4))) unsigned short ushort4v;
typedef __attribute__((ext_vector_type(4))) float f32x4;

__device__ __forceinline__ unsigned short f2bf(float f){
    unsigned u = __float_as_uint(f);
    unsigned r = (u + 0x7FFFu + ((u >> 16) & 1u)) >> 16;
    return (unsigned short)r;
}
__device__ __forceinline__ float bf2f(unsigned short u){
    return __uint_as_float(((unsigned)u) << 16);
}

// ---------- k_pre: fused x-transpose + weight prep + psum zero ----------
// blocks [0,528): x NCHW fp32 -> zero-padded NHWC bf16 [8][66][66][128]
//   XCD-affine: batch = bid & 7 so batch b's xTp slice (1.1 MB) lands in XCD b's L2.
// blocks [528,1250): wAv swizzled [kc][q4][r128][j8], w27A [kc][m32][kk32], biasom, psum=0
__global__ void k_pre(const float* __restrict__ x, unsigned short* __restrict__ xTp,
                      const float* __restrict__ w_reg, const float* __restrict__ w_off,
                      const float* __restrict__ w_mod, const float* __restrict__ b_off,
                      const float* __restrict__ b_mod,
                      unsigned short* __restrict__ wAv, unsigned short* __restrict__ w27A,
                      float* __restrict__ biasom, float* __restrict__ psum){
    int tid = threadIdx.x;
    if (blockIdx.x >= 528){
        int i = (blockIdx.x - 528) * 256 + tid;
        if (i < 147456){
            int kc = i >> 12, rem = i & 4095;
            int q = rem >> 10, r = (rem >> 3) & 127, j = rem & 7;
            int kk = kc * 32 + q * 8 + j, k = kk >> 7, c = kk & 127;
            wAv[i] = f2bf(w_reg[r * 1152 + c * 9 + k]);
        } else if (i < 147456 + 36864){
            int j2 = i - 147456;
            int kc = j2 >> 10, rem = j2 & 1023, m = rem >> 5, kkl = rem & 31;
            int kk = kc * 32 + kkl, k = kk >> 7, c = kk & 127;
            float v = 0.f;
            if (m < 18) v = w_off[m * 1152 + c * 9 + k];
            else if (m < 27) v = w_mod[(m - 18) * 1152 + c * 9 + k];
            w27A[j2] = f2bf(v);
        } else if (i < 147456 + 36864 + 32){
            int m = i - 147456 - 36864;
            biasom[m] = (m < 18) ? b_off[m] : (m < 27 ? b_mod[m - 18] : 0.f);
        } else if (i < 147456 + 36864 + 32 + 256){
            psum[i - 147456 - 36864 - 32] = 0.f;
        }
        return;
    }
    int bidx = blockIdx.x;
    int b = bidx & 7, hp = bidx >> 3;       // XCD-affine: batch = bid%8
    unsigned short* row = xTp + (size_t)(b * 66 + hp) * 66 * 128;
    if (hp == 0 || hp == 65){
        ushort8 z = {0,0,0,0,0,0,0,0};
        for (int i = tid; i < 66 * 128 / 8; i += 256) ((ushort8*)row)[i] = z;
        return;
    }
    int h = hp - 1;
    __shared__ unsigned short s[64 * 136];
    int w = tid & 63, c0 = tid >> 6;
    for (int cc = 0; cc < 128; cc += 4){
        int c = cc + c0;
        s[w * 136 + c] = f2bf(x[(size_t)(b * 128 + c) * HWi + h * 64 + w]);
    }
    __syncthreads();
    if (tid < 32){
        ushort8 z = {0,0,0,0,0,0,0,0};
        int wp = (tid < 16) ? 0 : 65;
        int sg = tid & 15;
        *(ushort8*)(row + wp * 128 + sg * 8) = z;
    }
    for (int it = tid; it < 1024; it += 256){
        int w2 = it >> 4, sg = it & 15;
        *(ushort8*)(row + (w2 + 1) * 128 + sg * 8) = *(const ushort8*)(s + w2 * 136 + sg * 8);
    }
}

// ---------- k_fused: 27-conv (phase 1, K-split) + deformable conv GEMM (phase 2) ----------
// One block owns one 64-pixel tile end-to-end: computes its own OM in LDS (no global
// round-trip, no separate kernel), then samples + GEMMs.
__global__ __launch_bounds__(512, 4) void k_fused(const unsigned short* __restrict__ xTp,
        const unsigned short* __restrict__ w27A, const float* __restrict__ biasom,
        const unsigned short* __restrict__ wAv, const float* __restrict__ b_reg,
        unsigned short* __restrict__ ybf, float* __restrict__ psum){
    __shared__ char smem[49152];
    int tid = threadIdx.x;
    // XCD-affine swizzle: 512 blocks = 8 batches x 64 rows; batch (bid&7) -> XCD (bid&7)
    int lb = (blockIdx.x & 7) * 64 + (blockIdx.x >> 3);
    int n0 = lb * 64;
    int b = n0 >> 12, h = (n0 >> 6) & 63;

    // ================= Phase 1: offset/mod conv, K split across 2 groups =================
    // grp0: kc 0..17, grp1: kc 18..35. Each group: M=32 x N=64 x K=576 MFMA GEMM.
    {
        int grp = tid >> 8, gt = tid & 255;
        unsigned short* pA = (unsigned short*)(smem + grp * 15360);          // [2][32*PADu] = 5120 B
        unsigned short* pB = (unsigned short*)(smem + grp * 15360 + 5120);   // [2][64*PADu] = 10240 B
        int wvg = gt >> 6, lane = gt & 63, quad = lane >> 4, l16 = lane & 15;
        int nl = gt >> 2, sg = gt & 3;
        f32x4 acc0 = {0.f,0.f,0.f,0.f}, acc1 = {0.f,0.f,0.f,0.f};
        ushort8 rA, rB;
        int kc0 = grp * 18;
        auto p1load = [&](int i){
            int kc = kc0 + i;
            int k = kc >> 2, cb = (kc & 3) << 5;
            int ki = k / 3, kj = k - ki * 3;
            if (gt < 128) rA = *(const ushort8*)(w27A + kc * 1024 + gt * 8);
            int rowi = (b * 66 + h + ki) * 66 + (nl + kj);
            rB = *(const ushort8*)(xTp + (size_t)rowi * 128 + cb + sg * 8);
        };
        p1load(0);
        for (int i = 0; i < 18; i++){
            int p = i & 1;
            if (gt < 128) *(ushort8*)(pA + p * 1280 + (gt >> 2) * PADu + (gt & 3) * 8) = rA;
            *(ushort8*)(pB + p * 2560 + nl * PADu + sg * 8) = rB;
            if (i + 1 < 18) p1load(i + 1);
            __syncthreads();
            short8 bfrag = *(const short8*)(pB + p * 2560 + (wvg * 16 + l16) * PADu + quad * 8);
            short8 a0 = *(const short8*)(pA + p * 1280 + l16 * PADu + quad * 8);
            short8 a1 = *(const short8*)(pA + p * 1280 + (16 + l16) * PADu + quad * 8);
            acc0 = __builtin_amdgcn_mfma_f32_16x16x32_bf16(a0, bfrag, acc0, 0, 0, 0);
            acc1 = __builtin_amdgcn_mfma_f32_16x16x32_bf16(a1, bfrag, acc1, 0, 0, 0);
        }
        // K-reduce: grp1 dumps partials, grp0 adds + bias/sigmoid -> s_OM (bf16, [64][32])
        float* s_red = (float*)(smem + 30720);     // [64][32] fp32 = 8192 B (after p1 tiles)
        int npx = wvg * 16 + l16;
        if (grp == 1){
            #pragma unroll
            for (int t = 0; t < 2; t++){
                f32x4 a = t ? acc1 : acc0;
                #pragma unroll
                for (int r = 0; r < 4; r++)
                    s_red[npx * 32 + t * 16 + quad * 4 + r] = a[r];
            }
        }
        __syncthreads();   // also guarantees all p1 tile reads are done
        if (grp == 0){
            unsigned short* s_OM = (unsigned short*)smem;  // [64][32] bf16 at [0,4096)
            #pragma unroll
            for (int t = 0; t < 2; t++){
                f32x4 a = t ? acc1 : acc0;
                #pragma unroll
                for (int r = 0; r < 4; r++){
                    int oc = t * 16 + quad * 4 + r;
                    float v = a[r] + s_red[npx * 32 + oc] + biasom[oc];
                    if (oc >= 18) v = 2.f / (1.f + expf(-v));   // same math as old k_gemm27
                    s_OM[npx * 32 + oc] = f2bf(v);
                }
            }
        }
        __syncthreads();
    }

    // ================= Phase 2: deformable sampling + 128-out GEMM =================
    unsigned short* sA = (unsigned short*)smem;             // [2][128*40] = 20480 B
    unsigned short* sB = (unsigned short*)(smem + 20480);   // [2][64*40]  = 10240 B
    int*   s_a0 = (int*)(smem + 30720);                     // [4][576]    = 9216 B
    float* s_w0 = (float*)(smem + 39936);                   // [4][576]    = 9216 B
    const unsigned short* s_OM = (const unsigned short*)smem;  // alias [64][32] (read-only here)

    for (int idx = tid; idx < 576; idx += 512){
        int k = idx >> 6, px = idx & 63;
        float dy = bf2f(s_OM[px * 32 + 2 * k]);
        float dx = bf2f(s_OM[px * 32 + 2 * k + 1]);
        float m  = bf2f(s_OM[px * 32 + 18 + k]);
        int ki = k / 3, kj = k - ki * 3;
        float py  = (float)(h - 1 + ki) + dy;
        float pxf = (float)(px - 1 + kj) + dx;
        float y0f = floorf(py), x0f = floorf(pxf);
        float ly = py - y0f, lx = pxf - x0f;
        int iy0 = (int)y0f, ix0 = (int)x0f;
        int cy0 = min(max(iy0 + 1, 0), 65), cy1 = min(max(iy0 + 2, 0), 65);
        int cx0 = min(max(ix0 + 1, 0), 65), cx1 = min(max(ix0 + 2, 0), 65);
        int rb = b * 66 * 66;
        s_a0[0 * 576 + idx] = ((rb + cy0 * 66) + cx0) * 128;
        s_a0[1 * 576 + idx] = ((rb + cy0 * 66) + cx1) * 128;
        s_a0[2 * 576 + idx] = ((rb + cy1 * 66) + cx0) * 128;
        s_a0[3 * 576 + idx] = ((rb + cy1 * 66) + cx1) * 128;
        s_w0[0 * 576 + idx] = (1.f - ly) * (1.f - lx) * m;
        s_w0[1 * 576 + idx] = (1.f - ly) * lx * m;
        s_w0[2 * 576 + idx] = ly * (1.f - lx) * m;
        s_w0[3 * 576 + idx] = ly * lx * m;
    }
    __syncthreads();

    int wv = tid >> 6, lane = tid & 63, quad = lane >> 4, l16 = lane & 15;
    int ocq = wv & 3, ng = wv >> 2;
    int rA = tid & 127, qA = tid >> 7;            // sA staging role
    int spx = (tid & 255) >> 2, scq = tid & 3;    // sampling role (tid<256)
    bool samp = (tid < 256);

    f32x4 acc00 = {0.f,0.f,0.f,0.f}, acc01 = {0.f,0.f,0.f,0.f};
    f32x4 acc10 = {0.f,0.f,0.f,0.f}, acc11 = {0.f,0.f,0.f,0.f};

    ushort8 rW, rc0, rc1, rc2, rc3;
    float w0 = 0.f, w1 = 0.f, w2 = 0.f, w3 = 0.f;

    auto loadNext = [&](int kcn){
        rW = *(const ushort8*)(wAv + kcn * 4096 + tid * 8);
        if (samp){
            int k = kcn >> 2, cb = (kcn & 3) << 5;
            int idx = k * 64 + spx;
            int co = cb + scq * 8;
            w0 = s_w0[0 * 576 + idx]; w1 = s_w0[1 * 576 + idx];
            w2 = s_w0[2 * 576 + idx]; w3 = s_w0[3 * 576 + idx];
            rc0 = *(const ushort8*)(xTp + s_a0[0 * 576 + idx] + co);
            rc1 = *(const ushort8*)(xTp + s_a0[1 * 576 + idx] + co);
            rc2 = *(const ushort8*)(xTp + s_a0[2 * 576 + idx] + co);
            rc3 = *(const ushort8*)(xTp + s_a0[3 * 576 + idx] + co);
        }
    };
    loadNext(0);
    for (int kc = 0; kc < NKC; kc++){
        int p = kc & 1;
        *(ushort8*)(sA + p * 5120 + rA * PADu + qA * 8) = rW;
        if (samp){
            ushort8 o;
            #pragma unroll
            for (int s = 0; s < 8; s++){
                float v = w0 * bf2f(rc0[s]) + w1 * bf2f(rc1[s])
                        + w2 * bf2f(rc2[s]) + w3 * bf2f(rc3[s]);
                o[s] = f2bf(v);
            }
            *(ushort8*)(sB + p * 2560 + spx * PADu + scq * 8) = o;
        }
        if (kc + 1 < NKC) loadNext(kc + 1);
        __syncthreads();
        const unsigned short* A = sA + p * 5120;
        const unsigned short* Bn = sB + p * 2560;
        short8 a0 = *(const short8*)(A + (ocq * 32 + l16) * PADu + quad * 8);
        short8 a1 = *(const short8*)(A + (ocq * 32 + 16 + l16) * PADu + quad * 8);
        short8 b0 = *(const short8*)(Bn + (ng * 32 + l16) * PADu + quad * 8);
        short8 b1 = *(const short8*)(Bn + (ng * 32 + 16 + l16) * PADu + quad * 8);
        acc00 = __builtin_amdgcn_mfma_f32_16x16x32_bf16(a0, b0, acc00, 0, 0, 0);
        acc01 = __builtin_amdgcn_mfma_f32_16x16x32_bf16(a0, b1, acc01, 0, 0, 0);
        acc10 = __builtin_amdgcn_mfma_f32_16x16x32_bf16(a1, b0, acc10, 0, 0, 0);
        acc11 = __builtin_amdgcn_mfma_f32_16x16x32_bf16(a1, b1, acc11, 0, 0, 0);
    }

    __syncthreads();
    float* ls = (float*)smem;   // [128][68] fp32 = 34816 B (overlaps tiles; done with them)
    int sp0 = h * 64;
    #pragma unroll
    for (int to = 0; to < 2; to++){
        #pragma unroll
        for (int tn = 0; tn < 2; tn++){
            f32x4 a = to ? (tn ? acc11 : acc10) : (tn ? acc01 : acc00);
            int nl = ng * 32 + tn * 16 + l16;
            #pragma unroll
            for (int r = 0; r < 4; r++){
                int oc = ocq * 32 + to * 16 + quad * 4 + r;
                float v = a[r] + b_reg[oc];
                ybf[(size_t)(b * 128 + oc) * HWi + sp0 + nl] = f2bf(v);
                ls[oc * 68 + nl] = v;
            }
        }
    }
    __syncthreads();
    if (tid < 128){
        int oc = tid;
        float s = 0.f, s2 = 0.f;
        #pragma unroll 8
        for (int nl = 0; nl < 64; nl++){
            float v = ls[oc * 68 + nl];
            s += v; s2 = fmaf(v, v, s2);
        }
        atomicAdd(&psum[oc], s);
        atomicAdd(&psum[128 + oc], s2);
    }
}

// ---------- k_apply: BN (stats inline from psum) + affine + relu -> fp32 ----------
__global__ void k_apply(const unsigned short* __restrict__ ybf, const float* __restrict__ psum,
                        const float* __restrict__ gamma, const float* __restrict__ beta,
                        float* __restrict__ out){
    // XCD-affine swizzle: read ybf from the XCD whose k_fused blocks (same batch) wrote it.
    int lb = ((int)blockIdx.x & 7) * 256 + ((int)blockIdx.x >> 3);
    int e8 = (lb * 256 + (int)threadIdx.x) * 8;
    int c = (e8 >> 12) & 127;
    ushort8 u = *(const ushort8*)(ybf + e8);
    float s = psum[c], s2 = psum[128 + c];
    float mean = s * (1.f / 32768.f);
    float var  = s2 * (1.f / 32768.f) - mean * mean;
    float rs = rsqrtf(var + 1e-5f);
    float g = gamma[c] * rs;
    float bt = beta[c] - mean * g;
    float4 lo, hi;
    lo.x = fmaxf(fmaf(bf2f(u[0]), g, bt), 0.f);
    lo.y = fmaxf(fmaf(bf2f(u[1]), g, bt), 0.f);
    lo.z = fmaxf(fmaf(bf2f(u[2]), g, bt), 0.f);
    lo.w = fmaxf(fmaf(bf2f(u[3]), g, bt), 0.f);
    hi.x = fmaxf(fmaf(bf2f(u[4]), g, bt), 0.f);
    hi.y = fmaxf(fmaf(bf2f(u[5]), g, bt), 0.f);
    hi.z = fmaxf(fmaf(bf2f(u[6]), g, bt), 0.f);
    hi.w = fmaxf(fmaf(bf2f(u[7]), g, bt), 0.f);
    *(float4*)(out + e8)     = lo;
    *(float4*)(out + e8 + 4) = hi;
}

extern "C" void kernel_launch(void* const* d_in, const int* in_sizes, int n_in,
                              void* d_out, int out_size, void* d_ws, size_t ws_size,
                              hipStream_t stream){
    const float* x     = (const float*)d_in[0];
    const float* w_off = (const float*)d_in[1];
    const float* b_off = (const float*)d_in[2];
    const float* w_mod = (const float*)d_in[3];
    const float* b_mod = (const float*)d_in[4];
    const float* w_reg = (const float*)d_in[5];
    const float* b_reg = (const float*)d_in[6];
    const float* gamma = (const float*)d_in[7];
    const float* beta  = (const float*)d_in[8];

    char* wsb = (char*)d_ws;
    unsigned short* xTp   = (unsigned short*)(wsb);                    // 8,921,088 B
    unsigned short* ybf   = (unsigned short*)(wsb + 11018240);         // 8,388,608 B
    unsigned short* wAv   = (unsigned short*)(wsb + 19406848);         //   294,912 B
    unsigned short* w27A  = (unsigned short*)(wsb + 19701760);         //    73,728 B
    float*          biasom= (float*)(wsb + 19775488);                  //       128 B
    float*          psum  = (float*)(wsb + 19775616);                  //     1,024 B
    float* out = (float*)d_out;

    hipLaunchKernelGGL(k_pre,   dim3(1250), dim3(256), 0, stream, x, xTp, w_reg, w_off, w_mod, b_off, b_mod, wAv, w27A, biasom, psum);
    hipLaunchKernelGGL(k_fused, dim3(512),  dim3(512), 0, stream, xTp, w27A, biasom, wAv, b_reg, ybf, psum);
    hipLaunchKernelGGL(k_apply, dim3(2048), dim3(256), 0, stream, ybf, psum, gamma, beta, out);
}

// Round 4
// 134.058 us; speedup vs baseline: 1.0858x; 1.0230x over previous
//
#include <hip/hip_runtime.h>
#include <math.h>

#define H 64
#define W 64
#define C 128
#define NB 8
#define COUT 128
#define HWi 4096
#define NKC 36
#define PADu 40          // LDS row pitch in ushorts (80B = 5 superbanks, conflict-free b128)

typedef __attribute__((ext_vector_type(8))) short short8;
typedef __attribute__((ext_vector_type(8))) unsigned short ushort8;
typedef __attribute__((ext_vector_type(4))) unsigned short ushort4v;
typedef __attribute__((ext_vector_type(4))) float f32x4;

__device__ __forceinline__ unsigned short f2bf(float f){
    unsigned u = __float_as_uint(f);
    unsigned r = (u + 0x7FFFu + ((u >> 16) & 1u)) >> 16;
    return (unsigned short)r;
}
__device__ __forceinline__ float bf2f(unsigned short u){
    return __uint_as_float(((unsigned)u) << 16);
}

// ---------- k_pre: fused x-transpose + weight prep + psum zero ----------
// blocks [0,528): x NCHW fp32 -> zero-padded NHWC bf16 [8][66][66][128]
//   XCD-affine: batch = bid & 7 so batch b's xTp slice (1.1 MB) lands in XCD b's L2.
// blocks [528,1250): wAv swizzled [kc][q4][r128][j8], w27A [kc][m32][kk32], biasom, psum=0
__global__ void k_pre(const float* __restrict__ x, unsigned short* __restrict__ xTp,
                      const float* __restrict__ w_reg, const float* __restrict__ w_off,
                      const float* __restrict__ w_mod, const float* __restrict__ b_off,
                      const float* __restrict__ b_mod,
                      unsigned short* __restrict__ wAv, unsigned short* __restrict__ w27A,
                      float* __restrict__ biasom, float* __restrict__ psum){
    int tid = threadIdx.x;
    if (blockIdx.x >= 528){
        int i = (blockIdx.x - 528) * 256 + tid;
        if (i < 147456){
            int kc = i >> 12, rem = i & 4095;
            int q = rem >> 10, r = (rem >> 3) & 127, j = rem & 7;
            int kk = kc * 32 + q * 8 + j, k = kk >> 7, c = kk & 127;
            wAv[i] = f2bf(w_reg[r * 1152 + c * 9 + k]);
        } else if (i < 147456 + 36864){
            int j2 = i - 147456;
            int kc = j2 >> 10, rem = j2 & 1023, m = rem >> 5, kkl = rem & 31;
            int kk = kc * 32 + kkl, k = kk >> 7, c = kk & 127;
            float v = 0.f;
            if (m < 18) v = w_off[m * 1152 + c * 9 + k];
            else if (m < 27) v = w_mod[(m - 18) * 1152 + c * 9 + k];
            w27A[j2] = f2bf(v);
        } else if (i < 147456 + 36864 + 32){
            int m = i - 147456 - 36864;
            biasom[m] = (m < 18) ? b_off[m] : (m < 27 ? b_mod[m - 18] : 0.f);
        } else if (i < 147456 + 36864 + 32 + 256){
            psum[i - 147456 - 36864 - 32] = 0.f;
        }
        return;
    }
    int bidx = blockIdx.x;
    int b = bidx & 7, hp = bidx >> 3;       // XCD-affine: batch = bid%8
    unsigned short* row = xTp + (size_t)(b * 66 + hp) * 66 * 128;
    if (hp == 0 || hp == 65){
        ushort8 z = {0,0,0,0,0,0,0,0};
        for (int i = tid; i < 66 * 128 / 8; i += 256) ((ushort8*)row)[i] = z;
        return;
    }
    int h = hp - 1;
    __shared__ unsigned short s[64 * 136];
    int w = tid & 63, c0 = tid >> 6;
    for (int cc = 0; cc < 128; cc += 4){
        int c = cc + c0;
        s[w * 136 + c] = f2bf(x[(size_t)(b * 128 + c) * HWi + h * 64 + w]);
    }
    __syncthreads();
    if (tid < 32){
        ushort8 z = {0,0,0,0,0,0,0,0};
        int wp = (tid < 16) ? 0 : 65;
        int sg = tid & 15;
        *(ushort8*)(row + wp * 128 + sg * 8) = z;
    }
    for (int it = tid; it < 1024; it += 256){
        int w2 = it >> 4, sg = it & 15;
        *(ushort8*)(row + (w2 + 1) * 128 + sg * 8) = *(const ushort8*)(s + w2 * 136 + sg * 8);
    }
}

// ---------- k_fused: 27-conv (phase 1, K-split) + deformable conv GEMM (phase 2) ----------
// Phase 2 processes kc in PAIRS (even/odd share the same kernel tap -> same corners and
// weights): one staging phase = 64px x 64ch, sampling spread across all 512 threads,
// 18 barriers instead of 36, 8 MFMA per barrier.
__global__ __launch_bounds__(512, 4) void k_fused(const unsigned short* __restrict__ xTp,
        const unsigned short* __restrict__ w27A, const float* __restrict__ biasom,
        const unsigned short* __restrict__ wAv, const float* __restrict__ b_reg,
        unsigned short* __restrict__ ybf, float* __restrict__ psum){
    __shared__ char smem[79872];
    int tid = threadIdx.x;
    // XCD-affine swizzle: 512 blocks = 8 batches x 64 rows; batch (bid&7) -> XCD (bid&7)
    int lb = (blockIdx.x & 7) * 64 + (blockIdx.x >> 3);
    int n0 = lb * 64;
    int b = n0 >> 12, h = (n0 >> 6) & 63;

    // ================= Phase 1: offset/mod conv, K split across 2 groups =================
    // grp0: kc 0..17, grp1: kc 18..35. Each group: M=32 x N=64 x K=576 MFMA GEMM.
    {
        int grp = tid >> 8, gt = tid & 255;
        unsigned short* pA = (unsigned short*)(smem + grp * 15360);          // [2][32*PADu] = 5120 B
        unsigned short* pB = (unsigned short*)(smem + grp * 15360 + 5120);   // [2][64*PADu] = 10240 B
        int wvg = gt >> 6, lane = gt & 63, quad = lane >> 4, l16 = lane & 15;
        int nl = gt >> 2, sg = gt & 3;
        f32x4 acc0 = {0.f,0.f,0.f,0.f}, acc1 = {0.f,0.f,0.f,0.f};
        ushort8 rA, rB;
        int kc0 = grp * 18;
        auto p1load = [&](int i){
            int kc = kc0 + i;
            int k = kc >> 2, cb = (kc & 3) << 5;
            int ki = k / 3, kj = k - ki * 3;
            if (gt < 128) rA = *(const ushort8*)(w27A + kc * 1024 + gt * 8);
            int rowi = (b * 66 + h + ki) * 66 + (nl + kj);
            rB = *(const ushort8*)(xTp + (size_t)rowi * 128 + cb + sg * 8);
        };
        p1load(0);
        for (int i = 0; i < 18; i++){
            int p = i & 1;
            if (gt < 128) *(ushort8*)(pA + p * 1280 + (gt >> 2) * PADu + (gt & 3) * 8) = rA;
            *(ushort8*)(pB + p * 2560 + nl * PADu + sg * 8) = rB;
            if (i + 1 < 18) p1load(i + 1);
            __syncthreads();
            short8 bfrag = *(const short8*)(pB + p * 2560 + (wvg * 16 + l16) * PADu + quad * 8);
            short8 a0 = *(const short8*)(pA + p * 1280 + l16 * PADu + quad * 8);
            short8 a1 = *(const short8*)(pA + p * 1280 + (16 + l16) * PADu + quad * 8);
            acc0 = __builtin_amdgcn_mfma_f32_16x16x32_bf16(a0, bfrag, acc0, 0, 0, 0);
            acc1 = __builtin_amdgcn_mfma_f32_16x16x32_bf16(a1, bfrag, acc1, 0, 0, 0);
        }
        // K-reduce: grp1 dumps partials, grp0 adds + bias/sigmoid -> s_OM (bf16, [64][32])
        float* s_red = (float*)(smem + 30720);     // [64][32] fp32 = 8192 B (after p1 tiles)
        int npx = wvg * 16 + l16;
        if (grp == 1){
            #pragma unroll
            for (int t = 0; t < 2; t++){
                f32x4 a = t ? acc1 : acc0;
                #pragma unroll
                for (int r = 0; r < 4; r++)
                    s_red[npx * 32 + t * 16 + quad * 4 + r] = a[r];
            }
        }
        __syncthreads();   // also guarantees all p1 tile reads are done
        if (grp == 0){
            unsigned short* s_OM = (unsigned short*)smem;  // [64][32] bf16 at [0,4096)
            #pragma unroll
            for (int t = 0; t < 2; t++){
                f32x4 a = t ? acc1 : acc0;
                #pragma unroll
                for (int r = 0; r < 4; r++){
                    int oc = t * 16 + quad * 4 + r;
                    float v = a[r] + s_red[npx * 32 + oc] + biasom[oc];
                    if (oc >= 18) v = 2.f / (1.f + expf(-v));   // same math as old k_gemm27
                    s_OM[npx * 32 + oc] = f2bf(v);
                }
            }
        }
        __syncthreads();
    }

    // ================= Phase 2: deformable sampling + 128-out GEMM (paired kc) ============
    unsigned short* sA = (unsigned short*)smem;              // [2][2][128*40] = 40960 B
    unsigned short* sB = (unsigned short*)(smem + 40960);    // [2][2][64*40]  = 20480 B
    int*   s_a0 = (int*)(smem + 61440);                      // [4][576] = 9216 B
    float* s_w0 = (float*)(smem + 70656);                    // [4][576] = 9216 B  (ends 79872)
    const unsigned short* s_OM = (const unsigned short*)smem;  // alias [64][32] (prologue only)

    for (int idx = tid; idx < 576; idx += 512){
        int k = idx >> 6, px = idx & 63;
        float dy = bf2f(s_OM[px * 32 + 2 * k]);
        float dx = bf2f(s_OM[px * 32 + 2 * k + 1]);
        float m  = bf2f(s_OM[px * 32 + 18 + k]);
        int ki = k / 3, kj = k - ki * 3;
        float py  = (float)(h - 1 + ki) + dy;
        float pxf = (float)(px - 1 + kj) + dx;
        float y0f = floorf(py), x0f = floorf(pxf);
        float ly = py - y0f, lx = pxf - x0f;
        int iy0 = (int)y0f, ix0 = (int)x0f;
        int cy0 = min(max(iy0 + 1, 0), 65), cy1 = min(max(iy0 + 2, 0), 65);
        int cx0 = min(max(ix0 + 1, 0), 65), cx1 = min(max(ix0 + 2, 0), 65);
        int rb = b * 66 * 66;
        s_a0[0 * 576 + idx] = ((rb + cy0 * 66) + cx0) * 128;
        s_a0[1 * 576 + idx] = ((rb + cy0 * 66) + cx1) * 128;
        s_a0[2 * 576 + idx] = ((rb + cy1 * 66) + cx0) * 128;
        s_a0[3 * 576 + idx] = ((rb + cy1 * 66) + cx1) * 128;
        s_w0[0 * 576 + idx] = (1.f - ly) * (1.f - lx) * m;
        s_w0[1 * 576 + idx] = (1.f - ly) * lx * m;
        s_w0[2 * 576 + idx] = ly * (1.f - lx) * m;
        s_w0[3 * 576 + idx] = ly * lx * m;
    }
    __syncthreads();

    int wv = tid >> 6, lane = tid & 63, quad = lane >> 4, l16 = lane & 15;
    int ocq = wv & 3, ng = wv >> 2;
    int rA = tid & 127, qA = tid >> 7;            // sA staging role (all 512)
    int px = tid >> 3, cg = tid & 7;              // sampling role (all 512): 8 ch of one px

    f32x4 acc00 = {0.f,0.f,0.f,0.f}, acc01 = {0.f,0.f,0.f,0.f};
    f32x4 acc10 = {0.f,0.f,0.f,0.f}, acc11 = {0.f,0.f,0.f,0.f};

    ushort8 rW0, rW1, rc0, rc1, rc2, rc3;
    float w0 = 0.f, w1 = 0.f, w2 = 0.f, w3 = 0.f;

    // pair j covers kc = 2j, 2j+1 -> same tap k = j>>1, channel halves (j&1)*64 + {0..63}
    auto loadNextP = [&](int j){
        rW0 = *(const ushort8*)(wAv + (size_t)(2 * j) * 4096 + tid * 8);
        rW1 = *(const ushort8*)(wAv + (size_t)(2 * j + 1) * 4096 + tid * 8);
        int k = j >> 1, cb = (j & 1) << 6;
        int idx = k * 64 + px;
        int co = cb + cg * 8;
        w0 = s_w0[0 * 576 + idx]; w1 = s_w0[1 * 576 + idx];
        w2 = s_w0[2 * 576 + idx]; w3 = s_w0[3 * 576 + idx];
        rc0 = *(const ushort8*)(xTp + s_a0[0 * 576 + idx] + co);
        rc1 = *(const ushort8*)(xTp + s_a0[1 * 576 + idx] + co);
        rc2 = *(const ushort8*)(xTp + s_a0[2 * 576 + idx] + co);
        rc3 = *(const ushort8*)(xTp + s_a0[3 * 576 + idx] + co);
    };
    loadNextP(0);
    for (int j = 0; j < 18; j++){
        int p = j & 1;
        unsigned short* sAp = sA + p * 10240;    // 2 planes x 5120 ushorts
        unsigned short* sBp = sB + p * 5120;     // 2 planes x 2560 ushorts
        *(ushort8*)(sAp + rA * PADu + qA * 8) = rW0;
        *(ushort8*)(sAp + 5120 + rA * PADu + qA * 8) = rW1;
        {
            ushort8 o;
            #pragma unroll
            for (int s = 0; s < 8; s++){
                float v = w0 * bf2f(rc0[s]) + w1 * bf2f(rc1[s])
                        + w2 * bf2f(rc2[s]) + w3 * bf2f(rc3[s]);
                o[s] = f2bf(v);
            }
            *(ushort8*)(sBp + (cg >> 2) * 2560 + px * PADu + (cg & 3) * 8) = o;
        }
        if (j + 1 < 18) loadNextP(j + 1);
        __syncthreads();
        #pragma unroll
        for (int u = 0; u < 2; u++){
            const unsigned short* A = sAp + u * 5120;
            const unsigned short* Bn = sBp + u * 2560;
            short8 a0 = *(const short8*)(A + (ocq * 32 + l16) * PADu + quad * 8);
            short8 a1 = *(const short8*)(A + (ocq * 32 + 16 + l16) * PADu + quad * 8);
            short8 b0 = *(const short8*)(Bn + (ng * 32 + l16) * PADu + quad * 8);
            short8 b1 = *(const short8*)(Bn + (ng * 32 + 16 + l16) * PADu + quad * 8);
            acc00 = __builtin_amdgcn_mfma_f32_16x16x32_bf16(a0, b0, acc00, 0, 0, 0);
            acc01 = __builtin_amdgcn_mfma_f32_16x16x32_bf16(a0, b1, acc01, 0, 0, 0);
            acc10 = __builtin_amdgcn_mfma_f32_16x16x32_bf16(a1, b0, acc10, 0, 0, 0);
            acc11 = __builtin_amdgcn_mfma_f32_16x16x32_bf16(a1, b1, acc11, 0, 0, 0);
        }
    }

    __syncthreads();
    float* ls = (float*)smem;   // [128][68] fp32 = 34816 B (overlaps tiles; done with them)
    int sp0 = h * 64;
    #pragma unroll
    for (int to = 0; to < 2; to++){
        #pragma unroll
        for (int tn = 0; tn < 2; tn++){
            f32x4 a = to ? (tn ? acc11 : acc10) : (tn ? acc01 : acc00);
            int nl = ng * 32 + tn * 16 + l16;
            #pragma unroll
            for (int r = 0; r < 4; r++){
                int oc = ocq * 32 + to * 16 + quad * 4 + r;
                float v = a[r] + b_reg[oc];
                ybf[(size_t)(b * 128 + oc) * HWi + sp0 + nl] = f2bf(v);
                ls[oc * 68 + nl] = v;
            }
        }
    }
    __syncthreads();
    if (tid < 128){
        int oc = tid;
        float s = 0.f, s2 = 0.f;
        #pragma unroll 8
        for (int nl = 0; nl < 64; nl++){
            float v = ls[oc * 68 + nl];
            s += v; s2 = fmaf(v, v, s2);
        }
        atomicAdd(&psum[oc], s);
        atomicAdd(&psum[128 + oc], s2);
    }
}

// ---------- k_apply: BN (stats inline from psum) + affine + relu -> fp32 ----------
__global__ void k_apply(const unsigned short* __restrict__ ybf, const float* __restrict__ psum,
                        const float* __restrict__ gamma, const float* __restrict__ beta,
                        float* __restrict__ out){
    // XCD-affine swizzle: read ybf from the XCD whose k_fused blocks (same batch) wrote it.
    int lb = ((int)blockIdx.x & 7) * 256 + ((int)blockIdx.x >> 3);
    int e8 = (lb * 256 + (int)threadIdx.x) * 8;
    int c = (e8 >> 12) & 127;
    ushort8 u = *(const ushort8*)(ybf + e8);
    float s = psum[c], s2 = psum[128 + c];
    float mean = s * (1.f / 32768.f);
    float var  = s2 * (1.f / 32768.f) - mean * mean;
    float rs = rsqrtf(var + 1e-5f);
    float g = gamma[c] * rs;
    float bt = beta[c] - mean * g;
    float4 lo, hi;
    lo.x = fmaxf(fmaf(bf2f(u[0]), g, bt), 0.f);
    lo.y = fmaxf(fmaf(bf2f(u[1]), g, bt), 0.f);
    lo.z = fmaxf(fmaf(bf2f(u[2]), g, bt), 0.f);
    lo.w = fmaxf(fmaf(bf2f(u[3]), g, bt), 0.f);
    hi.x = fmaxf(fmaf(bf2f(u[4]), g, bt), 0.f);
    hi.y = fmaxf(fmaf(bf2f(u[5]), g, bt), 0.f);
    hi.z = fmaxf(fmaf(bf2f(u[6]), g, bt), 0.f);
    hi.w = fmaxf(fmaf(bf2f(u[7]), g, bt), 0.f);
    *(float4*)(out + e8)     = lo;
    *(float4*)(out + e8 + 4) = hi;
}

extern "C" void kernel_launch(void* const* d_in, const int* in_sizes, int n_in,
                              void* d_out, int out_size, void* d_ws, size_t ws_size,
                              hipStream_t stream){
    const float* x     = (const float*)d_in[0];
    const float* w_off = (const float*)d_in[1];
    const float* b_off = (const float*)d_in[2];
    const float* w_mod = (const float*)d_in[3];
    const float* b_mod = (const float*)d_in[4];
    const float* w_reg = (const float*)d_in[5];
    const float* b_reg = (const float*)d_in[6];
    const float* gamma = (const float*)d_in[7];
    const float* beta  = (const float*)d_in[8];

    char* wsb = (char*)d_ws;
    unsigned short* xTp   = (unsigned short*)(wsb);                    // 8,921,088 B
    unsigned short* ybf   = (unsigned short*)(wsb + 11018240);         // 8,388,608 B
    unsigned short* wAv   = (unsigned short*)(wsb + 19406848);         //   294,912 B
    unsigned short* w27A  = (unsigned short*)(wsb + 19701760);         //    73,728 B
    float*          biasom= (float*)(wsb + 19775488);                  //       128 B
    float*          psum  = (float*)(wsb + 19775616);                  //     1,024 B
    float* out = (float*)d_out;

    hipLaunchKernelGGL(k_pre,   dim3(1250), dim3(256), 0, stream, x, xTp, w_reg, w_off, w_mod, b_off, b_mod, wAv, w27A, biasom, psum);
    hipLaunchKernelGGL(k_fused, dim3(512),  dim3(512), 0, stream, xTp, w27A, biasom, wAv, b_reg, ybf, psum);
    hipLaunchKernelGGL(k_apply, dim3(2048), dim3(256), 0, stream, ybf, psum, gamma, beta, out);
}

// Round 5
// 132.423 us; speedup vs baseline: 1.0992x; 1.0123x over previous
//
#include <hip/hip_runtime.h>
#include <math.h>

#define H 64
#define W 64
#define C 128
#define NB 8
#define COUT 128
#define HWi 4096
#define NKC 36
#define PADu 40          // LDS row pitch in ushorts (80B = 5 superbanks)

typedef __attribute__((ext_vector_type(8))) short short8;
typedef __attribute__((ext_vector_type(8))) unsigned short ushort8;
typedef __attribute__((ext_vector_type(4))) unsigned short ushort4v;
typedef __attribute__((ext_vector_type(4))) float f32x4;

__device__ __forceinline__ unsigned short f2bf(float f){
    unsigned u = __float_as_uint(f);
    unsigned r = (u + 0x7FFFu + ((u >> 16) & 1u)) >> 16;
    return (unsigned short)r;
}
__device__ __forceinline__ float bf2f(unsigned short u){
    return __uint_as_float(((unsigned)u) << 16);
}

// ---------- k_pre: fused x-transpose + weight prep + psum zero ----------
__global__ void k_pre(const float* __restrict__ x, unsigned short* __restrict__ xTp,
                      const float* __restrict__ w_reg, const float* __restrict__ w_off,
                      const float* __restrict__ w_mod, const float* __restrict__ b_off,
                      const float* __restrict__ b_mod,
                      unsigned short* __restrict__ wAv, unsigned short* __restrict__ w27A,
                      float* __restrict__ biasom, float* __restrict__ psum){
    int tid = threadIdx.x;
    if (blockIdx.x >= 528){
        int i = (blockIdx.x - 528) * 256 + tid;
        if (i < 147456){
            int kc = i >> 12, rem = i & 4095;
            int q = rem >> 10, r = (rem >> 3) & 127, j = rem & 7;
            int kk = kc * 32 + q * 8 + j, k = kk >> 7, c = kk & 127;
            wAv[i] = f2bf(w_reg[r * 1152 + c * 9 + k]);
        } else if (i < 147456 + 36864){
            int j2 = i - 147456;
            int kc = j2 >> 10, rem = j2 & 1023, m = rem >> 5, kkl = rem & 31;
            int kk = kc * 32 + kkl, k = kk >> 7, c = kk & 127;
            float v = 0.f;
            if (m < 18) v = w_off[m * 1152 + c * 9 + k];
            else if (m < 27) v = w_mod[(m - 18) * 1152 + c * 9 + k];
            w27A[j2] = f2bf(v);
        } else if (i < 147456 + 36864 + 32){
            int m = i - 147456 - 36864;
            biasom[m] = (m < 18) ? b_off[m] : (m < 27 ? b_mod[m - 18] : 0.f);
        } else if (i < 147456 + 36864 + 32 + 256){
            psum[i - 147456 - 36864 - 32] = 0.f;
        }
        return;
    }
    int bidx = blockIdx.x;
    int b = bidx & 7, hp = bidx >> 3;       // XCD-affine: batch = bid%8
    unsigned short* row = xTp + (size_t)(b * 66 + hp) * 66 * 128;
    if (hp == 0 || hp == 65){
        ushort8 z = {0,0,0,0,0,0,0,0};
        for (int i = tid; i < 66 * 128 / 8; i += 256) ((ushort8*)row)[i] = z;
        return;
    }
    int h = hp - 1;
    __shared__ unsigned short s[64 * 136];
    int w = tid & 63, c0 = tid >> 6;
    for (int cc = 0; cc < 128; cc += 4){
        int c = cc + c0;
        s[w * 136 + c] = f2bf(x[(size_t)(b * 128 + c) * HWi + h * 64 + w]);
    }
    __syncthreads();
    if (tid < 32){
        ushort8 z = {0,0,0,0,0,0,0,0};
        int wp = (tid < 16) ? 0 : 65;
        int sg = tid & 15;
        *(ushort8*)(row + wp * 128 + sg * 8) = z;
    }
    for (int it = tid; it < 1024; it += 256){
        int w2 = it >> 4, sg = it & 15;
        *(ushort8*)(row + (w2 + 1) * 128 + sg * 8) = *(const ushort8*)(s + w2 * 136 + sg * 8);
    }
}

// ---------- k_fused: 27-conv (phase 1) + deformable conv GEMM (phase 2) ----------
// This round: 2-deep register prefetch (loads for iter j+2 issued at iter j -> L2
// latency fully covered), sA chunk-XOR swizzle (8-way write conflict -> free),
// ls pitch 67 (stats-reduction reads 8-way -> free).
__global__ __launch_bounds__(512, 4) void k_fused(const unsigned short* __restrict__ xTp,
        const unsigned short* __restrict__ w27A, const float* __restrict__ biasom,
        const unsigned short* __restrict__ wAv, const float* __restrict__ b_reg,
        unsigned short* __restrict__ ybf, float* __restrict__ psum){
    __shared__ char smem[79872];
    int tid = threadIdx.x;
    // XCD-affine swizzle: 512 blocks = 8 batches x 64 rows; batch (bid&7) -> XCD (bid&7)
    int lb = (blockIdx.x & 7) * 64 + (blockIdx.x >> 3);
    int n0 = lb * 64;
    int b = n0 >> 12, h = (n0 >> 6) & 63;

    // ================= Phase 1: offset/mod conv, K split across 2 groups =================
    {
        int grp = tid >> 8, gt = tid & 255;
        unsigned short* pA = (unsigned short*)(smem + grp * 15360);          // [2][32*PADu]
        unsigned short* pB = (unsigned short*)(smem + grp * 15360 + 5120);   // [2][64*PADu]
        int wvg = gt >> 6, lane = gt & 63, quad = lane >> 4, l16 = lane & 15;
        int nl = gt >> 2, sg = gt & 3;
        f32x4 acc0 = {0.f,0.f,0.f,0.f}, acc1 = {0.f,0.f,0.f,0.f};
        int kc0 = grp * 18;
        auto p1load = [&](int i, ushort8& A8, ushort8& B8){
            int kc = kc0 + i;
            int k = kc >> 2, cb = (kc & 3) << 5;
            int ki = k / 3, kj = k - ki * 3;
            if (gt < 128) A8 = *(const ushort8*)(w27A + kc * 1024 + gt * 8);
            int rowi = (b * 66 + h + ki) * 66 + (nl + kj);
            B8 = *(const ushort8*)(xTp + (size_t)rowi * 128 + cb + sg * 8);
        };
        auto p1body = [&](int i, ushort8& A8, ushort8& B8){
            int p = i & 1;
            if (gt < 128) *(ushort8*)(pA + p * 1280 + (gt >> 2) * PADu + (gt & 3) * 8) = A8;
            *(ushort8*)(pB + p * 2560 + nl * PADu + sg * 8) = B8;
            if (i + 2 < 18) p1load(i + 2, A8, B8);   // 2-deep prefetch
            __syncthreads();
            short8 bfrag = *(const short8*)(pB + p * 2560 + (wvg * 16 + l16) * PADu + quad * 8);
            short8 a0 = *(const short8*)(pA + p * 1280 + l16 * PADu + quad * 8);
            short8 a1 = *(const short8*)(pA + p * 1280 + (16 + l16) * PADu + quad * 8);
            acc0 = __builtin_amdgcn_mfma_f32_16x16x32_bf16(a0, bfrag, acc0, 0, 0, 0);
            acc1 = __builtin_amdgcn_mfma_f32_16x16x32_bf16(a1, bfrag, acc1, 0, 0, 0);
        };
        ushort8 rA0, rB0, rA1, rB1;
        p1load(0, rA0, rB0);
        p1load(1, rA1, rB1);
        for (int ih = 0; ih < 9; ih++){
            p1body(ih * 2,     rA0, rB0);
            p1body(ih * 2 + 1, rA1, rB1);
        }
        // K-reduce: grp1 dumps partials, grp0 adds + bias/sigmoid -> s_OM (bf16, [64][32])
        float* s_red = (float*)(smem + 30720);     // [64][32] fp32 (after p1 tiles)
        int npx = wvg * 16 + l16;
        if (grp == 1){
            #pragma unroll
            for (int t = 0; t < 2; t++){
                f32x4 a = t ? acc1 : acc0;
                #pragma unroll
                for (int r = 0; r < 4; r++)
                    s_red[npx * 32 + t * 16 + quad * 4 + r] = a[r];
            }
        }
        __syncthreads();
        if (grp == 0){
            unsigned short* s_OM = (unsigned short*)smem;  // [64][32] bf16 at [0,4096)
            #pragma unroll
            for (int t = 0; t < 2; t++){
                f32x4 a = t ? acc1 : acc0;
                #pragma unroll
                for (int r = 0; r < 4; r++){
                    int oc = t * 16 + quad * 4 + r;
                    float v = a[r] + s_red[npx * 32 + oc] + biasom[oc];
                    if (oc >= 18) v = 2.f / (1.f + expf(-v));
                    s_OM[npx * 32 + oc] = f2bf(v);
                }
            }
        }
        __syncthreads();
    }

    // ================= Phase 2: deformable sampling + 128-out GEMM (paired kc) ============
    unsigned short* sA = (unsigned short*)smem;              // [2][2][128*40] = 40960 B
    unsigned short* sB = (unsigned short*)(smem + 40960);    // [2][2][64*40]  = 20480 B
    int*   s_a0 = (int*)(smem + 61440);                      // [4][576] = 9216 B
    float* s_w0 = (float*)(smem + 70656);                    // [4][576] = 9216 B
    const unsigned short* s_OM = (const unsigned short*)smem;  // alias (prologue only)

    for (int idx = tid; idx < 576; idx += 512){
        int k = idx >> 6, px_ = idx & 63;
        float dy = bf2f(s_OM[px_ * 32 + 2 * k]);
        float dx = bf2f(s_OM[px_ * 32 + 2 * k + 1]);
        float m  = bf2f(s_OM[px_ * 32 + 18 + k]);
        int ki = k / 3, kj = k - ki * 3;
        float py  = (float)(h - 1 + ki) + dy;
        float pxf = (float)(px_ - 1 + kj) + dx;
        float y0f = floorf(py), x0f = floorf(pxf);
        float ly = py - y0f, lx = pxf - x0f;
        int iy0 = (int)y0f, ix0 = (int)x0f;
        int cy0 = min(max(iy0 + 1, 0), 65), cy1 = min(max(iy0 + 2, 0), 65);
        int cx0 = min(max(ix0 + 1, 0), 65), cx1 = min(max(ix0 + 2, 0), 65);
        int rb = b * 66 * 66;
        s_a0[0 * 576 + idx] = ((rb + cy0 * 66) + cx0) * 128;
        s_a0[1 * 576 + idx] = ((rb + cy0 * 66) + cx1) * 128;
        s_a0[2 * 576 + idx] = ((rb + cy1 * 66) + cx0) * 128;
        s_a0[3 * 576 + idx] = ((rb + cy1 * 66) + cx1) * 128;
        s_w0[0 * 576 + idx] = (1.f - ly) * (1.f - lx) * m;
        s_w0[1 * 576 + idx] = (1.f - ly) * lx * m;
        s_w0[2 * 576 + idx] = ly * (1.f - lx) * m;
        s_w0[3 * 576 + idx] = ly * lx * m;
    }
    __syncthreads();

    int wv = tid >> 6, lane = tid & 63, quad = lane >> 4, l16 = lane & 15;
    int ocq = wv & 3, ng = wv >> 2;
    int rA = tid & 127, qA = tid >> 7;            // sA staging role (all 512)
    int cA = (qA ^ ((rA >> 3) & 3)) * 8;          // swizzled chunk: 8-way write -> free
    int px = tid >> 3, cg = tid & 7;              // sampling role (all 512): 8 ch of one px

    // hoisted, swizzle-matched fragment read offsets (loop-invariant)
    int rowA0 = ocq * 32 + l16, rowA1 = rowA0 + 16;
    int offA0 = rowA0 * PADu + (quad ^ ((rowA0 >> 3) & 3)) * 8;
    int offA1 = rowA1 * PADu + (quad ^ ((rowA1 >> 3) & 3)) * 8;
    int offB0 = (ng * 32 + l16) * PADu + quad * 8;
    int offB1 = (ng * 32 + 16 + l16) * PADu + quad * 8;

    f32x4 acc00 = {0.f,0.f,0.f,0.f}, acc01 = {0.f,0.f,0.f,0.f};
    f32x4 acc10 = {0.f,0.f,0.f,0.f}, acc11 = {0.f,0.f,0.f,0.f};

    // pair j covers kc = 2j, 2j+1 -> same tap k = j>>1, channel half (j&1)*64
    auto loadP = [&](int j, ushort8& W0, ushort8& W1, ushort8& C0, ushort8& C1,
                     ushort8& C2, ushort8& C3, float4& Wt){
        W0 = *(const ushort8*)(wAv + (size_t)(2 * j) * 4096 + tid * 8);
        W1 = *(const ushort8*)(wAv + (size_t)(2 * j + 1) * 4096 + tid * 8);
        int k = j >> 1, cb = (j & 1) << 6;
        int idx = k * 64 + px;
        int co = cb + cg * 8;
        Wt.x = s_w0[0 * 576 + idx]; Wt.y = s_w0[1 * 576 + idx];
        Wt.z = s_w0[2 * 576 + idx]; Wt.w = s_w0[3 * 576 + idx];
        C0 = *(const ushort8*)(xTp + s_a0[0 * 576 + idx] + co);
        C1 = *(const ushort8*)(xTp + s_a0[1 * 576 + idx] + co);
        C2 = *(const ushort8*)(xTp + s_a0[2 * 576 + idx] + co);
        C3 = *(const ushort8*)(xTp + s_a0[3 * 576 + idx] + co);
    };
    auto bodyP = [&](int j, ushort8& W0, ushort8& W1, ushort8& C0, ushort8& C1,
                     ushort8& C2, ushort8& C3, float4& Wt){
        int p = j & 1;
        unsigned short* sAp = sA + p * 10240;
        unsigned short* sBp = sB + p * 5120;
        *(ushort8*)(sAp + rA * PADu + cA) = W0;
        *(ushort8*)(sAp + 5120 + rA * PADu + cA) = W1;
        {
            ushort8 o;
            #pragma unroll
            for (int s = 0; s < 8; s++){
                float v = Wt.x * bf2f(C0[s]) + Wt.y * bf2f(C1[s])
                        + Wt.z * bf2f(C2[s]) + Wt.w * bf2f(C3[s]);
                o[s] = f2bf(v);
            }
            *(ushort8*)(sBp + (cg >> 2) * 2560 + px * PADu + (cg & 3) * 8) = o;
        }
        if (j + 2 < 18) loadP(j + 2, W0, W1, C0, C1, C2, C3, Wt);   // 2-deep prefetch
        __syncthreads();
        #pragma unroll
        for (int u = 0; u < 2; u++){
            const unsigned short* A = sAp + u * 5120;
            const unsigned short* Bn = sBp + u * 2560;
            short8 a0 = *(const short8*)(A + offA0);
            short8 a1 = *(const short8*)(A + offA1);
            short8 b0 = *(const short8*)(Bn + offB0);
            short8 b1 = *(const short8*)(Bn + offB1);
            acc00 = __builtin_amdgcn_mfma_f32_16x16x32_bf16(a0, b0, acc00, 0, 0, 0);
            acc01 = __builtin_amdgcn_mfma_f32_16x16x32_bf16(a0, b1, acc01, 0, 0, 0);
            acc10 = __builtin_amdgcn_mfma_f32_16x16x32_bf16(a1, b0, acc10, 0, 0, 0);
            acc11 = __builtin_amdgcn_mfma_f32_16x16x32_bf16(a1, b1, acc11, 0, 0, 0);
        }
    };

    ushort8 W0a, W1a, C0a, C1a, C2a, C3a, W0b, W1b, C0b, C1b, C2b, C3b;
    float4 Wta, Wtb;
    loadP(0, W0a, W1a, C0a, C1a, C2a, C3a, Wta);
    loadP(1, W0b, W1b, C0b, C1b, C2b, C3b, Wtb);
    for (int jh = 0; jh < 9; jh++){
        bodyP(jh * 2,     W0a, W1a, C0a, C1a, C2a, C3a, Wta);
        bodyP(jh * 2 + 1, W0b, W1b, C0b, C1b, C2b, C3b, Wtb);
    }

    __syncthreads();
    float* ls = (float*)smem;   // [128][67] fp32 = 34304 B (67: reduction reads 2-way/free)
    int sp0 = h * 64;
    #pragma unroll
    for (int to = 0; to < 2; to++){
        #pragma unroll
        for (int tn = 0; tn < 2; tn++){
            f32x4 a = to ? (tn ? acc11 : acc10) : (tn ? acc01 : acc00);
            int nl = ng * 32 + tn * 16 + l16;
            #pragma unroll
            for (int r = 0; r < 4; r++){
                int oc = ocq * 32 + to * 16 + quad * 4 + r;
                float v = a[r] + b_reg[oc];
                ybf[(size_t)(b * 128 + oc) * HWi + sp0 + nl] = f2bf(v);
                ls[oc * 67 + nl] = v;
            }
        }
    }
    __syncthreads();
    if (tid < 128){
        int oc = tid;
        float s = 0.f, s2 = 0.f;
        #pragma unroll 8
        for (int nl = 0; nl < 64; nl++){
            float v = ls[oc * 67 + nl];
            s += v; s2 = fmaf(v, v, s2);
        }
        atomicAdd(&psum[oc], s);
        atomicAdd(&psum[128 + oc], s2);
    }
}

// ---------- k_apply: BN (stats inline from psum) + affine + relu -> fp32 ----------
__global__ void k_apply(const unsigned short* __restrict__ ybf, const float* __restrict__ psum,
                        const float* __restrict__ gamma, const float* __restrict__ beta,
                        float* __restrict__ out){
    int lb = ((int)blockIdx.x & 7) * 256 + ((int)blockIdx.x >> 3);
    int e8 = (lb * 256 + (int)threadIdx.x) * 8;
    int c = (e8 >> 12) & 127;
    ushort8 u = *(const ushort8*)(ybf + e8);
    float s = psum[c], s2 = psum[128 + c];
    float mean = s * (1.f / 32768.f);
    float var  = s2 * (1.f / 32768.f) - mean * mean;
    float rs = rsqrtf(var + 1e-5f);
    float g = gamma[c] * rs;
    float bt = beta[c] - mean * g;
    float4 lo, hi;
    lo.x = fmaxf(fmaf(bf2f(u[0]), g, bt), 0.f);
    lo.y = fmaxf(fmaf(bf2f(u[1]), g, bt), 0.f);
    lo.z = fmaxf(fmaf(bf2f(u[2]), g, bt), 0.f);
    lo.w = fmaxf(fmaf(bf2f(u[3]), g, bt), 0.f);
    hi.x = fmaxf(fmaf(bf2f(u[4]), g, bt), 0.f);
    hi.y = fmaxf(fmaf(bf2f(u[5]), g, bt), 0.f);
    hi.z = fmaxf(fmaf(bf2f(u[6]), g, bt), 0.f);
    hi.w = fmaxf(fmaf(bf2f(u[7]), g, bt), 0.f);
    *(float4*)(out + e8)     = lo;
    *(float4*)(out + e8 + 4) = hi;
}

extern "C" void kernel_launch(void* const* d_in, const int* in_sizes, int n_in,
                              void* d_out, int out_size, void* d_ws, size_t ws_size,
                              hipStream_t stream){
    const float* x     = (const float*)d_in[0];
    const float* w_off = (const float*)d_in[1];
    const float* b_off = (const float*)d_in[2];
    const float* w_mod = (const float*)d_in[3];
    const float* b_mod = (const float*)d_in[4];
    const float* w_reg = (const float*)d_in[5];
    const float* b_reg = (const float*)d_in[6];
    const float* gamma = (const float*)d_in[7];
    const float* beta  = (const float*)d_in[8];

    char* wsb = (char*)d_ws;
    unsigned short* xTp   = (unsigned short*)(wsb);                    // 8,921,088 B
    unsigned short* ybf   = (unsigned short*)(wsb + 11018240);         // 8,388,608 B
    unsigned short* wAv   = (unsigned short*)(wsb + 19406848);         //   294,912 B
    unsigned short* w27A  = (unsigned short*)(wsb + 19701760);         //    73,728 B
    float*          biasom= (float*)(wsb + 19775488);                  //       128 B
    float*          psum  = (float*)(wsb + 19775616);                  //     1,024 B
    float* out = (float*)d_out;

    hipLaunchKernelGGL(k_pre,   dim3(1250), dim3(256), 0, stream, x, xTp, w_reg, w_off, w_mod, b_off, b_mod, wAv, w27A, biasom, psum);
    hipLaunchKernelGGL(k_fused, dim3(512),  dim3(512), 0, stream, xTp, w27A, biasom, wAv, b_reg, ybf, psum);
    hipLaunchKernelGGL(k_apply, dim3(2048), dim3(256), 0, stream, ybf, psum, gamma, beta, out);
}

// Round 6
// 130.323 us; speedup vs baseline: 1.1169x; 1.0161x over previous
//
#include <hip/hip_runtime.h>
#include <math.h>

#define H 64
#define W 64
#define C 128
#define NB 8
#define COUT 128
#define HWi 4096
#define NKC 36
#define PADu 40          // LDS row pitch in ushorts (80B = 5 superbanks)

typedef __attribute__((ext_vector_type(8))) short short8;
typedef __attribute__((ext_vector_type(8))) unsigned short ushort8;
typedef __attribute__((ext_vector_type(4))) unsigned int uint4v;
typedef __attribute__((ext_vector_type(4))) float f32x4;

__device__ __forceinline__ unsigned short f2bf(float f){
    unsigned u = __float_as_uint(f);
    unsigned r = (u + 0x7FFFu + ((u >> 16) & 1u)) >> 16;
    return (unsigned short)r;
}
__device__ __forceinline__ float bf2f(unsigned short u){
    return __uint_as_float(((unsigned)u) << 16);
}
__device__ __forceinline__ unsigned cvtpk_bf16(float lo, float hi){
    unsigned r;
    asm("v_cvt_pk_bf16_f32 %0, %1, %2" : "=v"(r) : "v"(lo), "v"(hi));
    return r;
}

// ---------- k_pre: fused x-transpose + weight prep + psum zero ----------
// blocks [0,528): x NCHW fp32 -> zero-padded NHWC bf16 [8][66][66][128], XCD-affine batch=bid&7
// blocks [528,1250): wAv [kc][q4][r128][j8] (fragment-major, direct-read by k_fused),
//                    w27A [kc][q4][m32][t8] (fragment-major), biasom, psum=0
__global__ void k_pre(const float* __restrict__ x, unsigned short* __restrict__ xTp,
                      const float* __restrict__ w_reg, const float* __restrict__ w_off,
                      const float* __restrict__ w_mod, const float* __restrict__ b_off,
                      const float* __restrict__ b_mod,
                      unsigned short* __restrict__ wAv, unsigned short* __restrict__ w27A,
                      float* __restrict__ biasom, float* __restrict__ psum){
    int tid = threadIdx.x;
    if (blockIdx.x >= 528){
        int i = (blockIdx.x - 528) * 256 + tid;
        if (i < 147456){
            int kc = i >> 12, rem = i & 4095;
            int q = rem >> 10, r = (rem >> 3) & 127, j = rem & 7;
            int kk = kc * 32 + q * 8 + j, k = kk >> 7, c = kk & 127;
            wAv[i] = f2bf(w_reg[r * 1152 + c * 9 + k]);
        } else if (i < 147456 + 36864){
            int j2 = i - 147456;
            // fragment-major: [kc][q][m][t] -> element (out-row m, ch q*8+t) of kc
            int kc = j2 >> 10, rem = j2 & 1023;
            int q = rem >> 8, m = (rem >> 3) & 31, t = rem & 7;
            int kkl = q * 8 + t;
            int kk = kc * 32 + kkl, k = kk >> 7, c = kk & 127;
            float v = 0.f;
            if (m < 18) v = w_off[m * 1152 + c * 9 + k];
            else if (m < 27) v = w_mod[(m - 18) * 1152 + c * 9 + k];
            w27A[j2] = f2bf(v);
        } else if (i < 147456 + 36864 + 32){
            int m = i - 147456 - 36864;
            biasom[m] = (m < 18) ? b_off[m] : (m < 27 ? b_mod[m - 18] : 0.f);
        } else if (i < 147456 + 36864 + 32 + 256){
            psum[i - 147456 - 36864 - 32] = 0.f;
        }
        return;
    }
    int bidx = blockIdx.x;
    int b = bidx & 7, hp = bidx >> 3;       // XCD-affine: batch = bid%8
    unsigned short* row = xTp + (size_t)(b * 66 + hp) * 66 * 128;
    if (hp == 0 || hp == 65){
        ushort8 z = {0,0,0,0,0,0,0,0};
        for (int i = tid; i < 66 * 128 / 8; i += 256) ((ushort8*)row)[i] = z;
        return;
    }
    int h = hp - 1;
    __shared__ unsigned short s[64 * 136];
    int w = tid & 63, c0 = tid >> 6;
    for (int cc = 0; cc < 128; cc += 4){
        int c = cc + c0;
        s[w * 136 + c] = f2bf(x[(size_t)(b * 128 + c) * HWi + h * 64 + w]);
    }
    __syncthreads();
    if (tid < 32){
        ushort8 z = {0,0,0,0,0,0,0,0};
        int wp = (tid < 16) ? 0 : 65;
        int sg = tid & 15;
        *(ushort8*)(row + wp * 128 + sg * 8) = z;
    }
    for (int it = tid; it < 1024; it += 256){
        int w2 = it >> 4, sg = it & 15;
        *(ushort8*)(row + (w2 + 1) * 128 + sg * 8) = *(const ushort8*)(s + w2 * 136 + sg * 8);
    }
}

// ---------- k_fused: 27-conv (phase 1) + deformable conv GEMM (phase 2) ----------
// This round: A-operands (static weights) loaded DIRECTLY from global per-wave
// (no LDS staging at all -> 2 ds_writes/thread/iter gone, LDS 79.9->38.9 KB),
// and sampled-value pack via v_cvt_pk_bf16_f32 (sampling VALU burst -30%).
__global__ __launch_bounds__(512, 4) void k_fused(const unsigned short* __restrict__ xTp,
        const unsigned short* __restrict__ w27A, const float* __restrict__ biasom,
        const unsigned short* __restrict__ wAv, const float* __restrict__ b_reg,
        unsigned short* __restrict__ ybf, float* __restrict__ psum){
    __shared__ char smem[38912];
    int tid = threadIdx.x;
    // XCD-affine swizzle: 512 blocks = 8 batches x 64 rows; batch (bid&7) -> XCD (bid&7)
    int lb = (blockIdx.x & 7) * 64 + (blockIdx.x >> 3);
    int n0 = lb * 64;
    int b = n0 >> 12, h = (n0 >> 6) & 63;

    // ================= Phase 1: offset/mod conv, K split across 2 groups =================
    {
        int grp = tid >> 8, gt = tid & 255;
        unsigned short* pB = (unsigned short*)(smem + grp * 10240);   // [2][64*PADu] per grp
        int wvg = gt >> 6, lane = gt & 63, quad = lane >> 4, l16 = lane & 15;
        int nl = gt >> 2, sg = gt & 3;
        f32x4 acc0 = {0.f,0.f,0.f,0.f}, acc1 = {0.f,0.f,0.f,0.f};
        int kc0 = grp * 18;
        auto p1load = [&](int i, ushort8& B8){
            int kc = kc0 + i;
            int k = kc >> 2, cb = (kc & 3) << 5;
            int ki = k / 3, kj = k - ki * 3;
            int rowi = (b * 66 + h + ki) * 66 + (nl + kj);
            B8 = *(const ushort8*)(xTp + (size_t)rowi * 128 + cb + sg * 8);
        };
        auto p1body = [&](int i, ushort8& B8){
            int p = i & 1;
            int kc = kc0 + i;
            // direct A-fragment loads (L1-hot, consumed after barrier)
            const unsigned short* wj = w27A + kc * 1024 + quad * 256;
            short8 a0 = *(const short8*)(wj + l16 * 8);
            short8 a1 = *(const short8*)(wj + (16 + l16) * 8);
            *(ushort8*)(pB + p * 2560 + nl * PADu + sg * 8) = B8;
            if (i + 2 < 18) p1load(i + 2, B8);   // 2-deep prefetch
            __syncthreads();
            short8 bfrag = *(const short8*)(pB + p * 2560 + (wvg * 16 + l16) * PADu + quad * 8);
            acc0 = __builtin_amdgcn_mfma_f32_16x16x32_bf16(a0, bfrag, acc0, 0, 0, 0);
            acc1 = __builtin_amdgcn_mfma_f32_16x16x32_bf16(a1, bfrag, acc1, 0, 0, 0);
        };
        ushort8 rB0, rB1;
        p1load(0, rB0);
        p1load(1, rB1);
        for (int ih = 0; ih < 9; ih++){
            p1body(ih * 2,     rB0);
            p1body(ih * 2 + 1, rB1);
        }
        // K-reduce: grp1 dumps partials, grp0 adds + bias/sigmoid -> s_OM (bf16, [64][32])
        float* s_red = (float*)(smem + 20480);     // [64][32] fp32
        int npx = wvg * 16 + l16;
        if (grp == 1){
            #pragma unroll
            for (int t = 0; t < 2; t++){
                f32x4 a = t ? acc1 : acc0;
                #pragma unroll
                for (int r = 0; r < 4; r++)
                    s_red[npx * 32 + t * 16 + quad * 4 + r] = a[r];
            }
        }
        __syncthreads();   // all pB reads done; s_red visible
        if (grp == 0){
            unsigned short* s_OM = (unsigned short*)smem;  // [64][32] bf16 at [0,4096)
            #pragma unroll
            for (int t = 0; t < 2; t++){
                f32x4 a = t ? acc1 : acc0;
                #pragma unroll
                for (int r = 0; r < 4; r++){
                    int oc = t * 16 + quad * 4 + r;
                    float v = a[r] + s_red[npx * 32 + oc] + biasom[oc];
                    if (oc >= 18) v = 2.f / (1.f + expf(-v));
                    s_OM[npx * 32 + oc] = f2bf(v);
                }
            }
        }
        __syncthreads();
    }

    // ================= Phase 2: deformable sampling + 128-out GEMM (paired kc) ============
    unsigned short* sB = (unsigned short*)smem;              // [2][2][64*PADu] = 20480 B
    int*   s_a0 = (int*)(smem + 20480);                      // [4][576] = 9216 B
    float* s_w0 = (float*)(smem + 29696);                    // [4][576] = 9216 B (ends 38912)
    const unsigned short* s_OM = (const unsigned short*)smem;  // alias [64][32] (prologue only)

    for (int idx = tid; idx < 576; idx += 512){
        int k = idx >> 6, px_ = idx & 63;
        float dy = bf2f(s_OM[px_ * 32 + 2 * k]);
        float dx = bf2f(s_OM[px_ * 32 + 2 * k + 1]);
        float m  = bf2f(s_OM[px_ * 32 + 18 + k]);
        int ki = k / 3, kj = k - ki * 3;
        float py  = (float)(h - 1 + ki) + dy;
        float pxf = (float)(px_ - 1 + kj) + dx;
        float y0f = floorf(py), x0f = floorf(pxf);
        float ly = py - y0f, lx = pxf - x0f;
        int iy0 = (int)y0f, ix0 = (int)x0f;
        int cy0 = min(max(iy0 + 1, 0), 65), cy1 = min(max(iy0 + 2, 0), 65);
        int cx0 = min(max(ix0 + 1, 0), 65), cx1 = min(max(ix0 + 2, 0), 65);
        int rb = b * 66 * 66;
        s_a0[0 * 576 + idx] = ((rb + cy0 * 66) + cx0) * 128;
        s_a0[1 * 576 + idx] = ((rb + cy0 * 66) + cx1) * 128;
        s_a0[2 * 576 + idx] = ((rb + cy1 * 66) + cx0) * 128;
        s_a0[3 * 576 + idx] = ((rb + cy1 * 66) + cx1) * 128;
        s_w0[0 * 576 + idx] = (1.f - ly) * (1.f - lx) * m;
        s_w0[1 * 576 + idx] = (1.f - ly) * lx * m;
        s_w0[2 * 576 + idx] = ly * (1.f - lx) * m;
        s_w0[3 * 576 + idx] = ly * lx * m;
    }
    __syncthreads();

    int wv = tid >> 6, lane = tid & 63, quad = lane >> 4, l16 = lane & 15;
    int ocq = wv & 3, ng = wv >> 2;
    int px = tid >> 3, cg = tid & 7;              // sampling role (all 512): 8 ch of one px

    int rowA0 = ocq * 32 + l16, rowA1 = rowA0 + 16;
    int offB0 = (ng * 32 + l16) * PADu + quad * 8;
    int offB1 = (ng * 32 + 16 + l16) * PADu + quad * 8;

    f32x4 acc00 = {0.f,0.f,0.f,0.f}, acc01 = {0.f,0.f,0.f,0.f};
    f32x4 acc10 = {0.f,0.f,0.f,0.f}, acc11 = {0.f,0.f,0.f,0.f};

    // pair j covers kc = 2j, 2j+1 -> same tap k = j>>1, channel half (j&1)*64
    auto loadP = [&](int j, ushort8& C0, ushort8& C1, ushort8& C2, ushort8& C3, float4& Wt){
        int k = j >> 1, cb = (j & 1) << 6;
        int idx = k * 64 + px;
        int co = cb + cg * 8;
        Wt.x = s_w0[0 * 576 + idx]; Wt.y = s_w0[1 * 576 + idx];
        Wt.z = s_w0[2 * 576 + idx]; Wt.w = s_w0[3 * 576 + idx];
        C0 = *(const ushort8*)(xTp + s_a0[0 * 576 + idx] + co);
        C1 = *(const ushort8*)(xTp + s_a0[1 * 576 + idx] + co);
        C2 = *(const ushort8*)(xTp + s_a0[2 * 576 + idx] + co);
        C3 = *(const ushort8*)(xTp + s_a0[3 * 576 + idx] + co);
    };
    auto bodyP = [&](int j, ushort8& C0, ushort8& C1, ushort8& C2, ushort8& C3, float4& Wt){
        int p = j & 1;
        unsigned short* sBp = sB + p * 5120;
        // direct A-fragment loads for this pair (issued early; L1-hot; used after barrier)
        const unsigned short* wj = wAv + (size_t)(2 * j) * 4096 + quad * 1024;
        short8 a00 = *(const short8*)(wj + rowA0 * 8);
        short8 a01 = *(const short8*)(wj + rowA1 * 8);
        short8 a10 = *(const short8*)(wj + 4096 + rowA0 * 8);
        short8 a11 = *(const short8*)(wj + 4096 + rowA1 * 8);
        // sampled B tile -> sB, packed bf16 via HW cvt_pk (RNE)
        uint4v ov;
        #pragma unroll
        for (int q = 0; q < 4; q++){
            float v0 = Wt.x * bf2f(C0[2*q])   + Wt.y * bf2f(C1[2*q])
                     + Wt.z * bf2f(C2[2*q])   + Wt.w * bf2f(C3[2*q]);
            float v1 = Wt.x * bf2f(C0[2*q+1]) + Wt.y * bf2f(C1[2*q+1])
                     + Wt.z * bf2f(C2[2*q+1]) + Wt.w * bf2f(C3[2*q+1]);
            ov[q] = cvtpk_bf16(v0, v1);
        }
        *(uint4v*)(sBp + (cg >> 2) * 2560 + px * PADu + (cg & 3) * 8) = ov;
        if (j + 2 < 18) loadP(j + 2, C0, C1, C2, C3, Wt);   // 2-deep gather prefetch
        __syncthreads();
        short8 b0 = *(const short8*)(sBp + offB0);
        short8 b1 = *(const short8*)(sBp + offB1);
        acc00 = __builtin_amdgcn_mfma_f32_16x16x32_bf16(a00, b0, acc00, 0, 0, 0);
        acc01 = __builtin_amdgcn_mfma_f32_16x16x32_bf16(a00, b1, acc01, 0, 0, 0);
        acc10 = __builtin_amdgcn_mfma_f32_16x16x32_bf16(a01, b0, acc10, 0, 0, 0);
        acc11 = __builtin_amdgcn_mfma_f32_16x16x32_bf16(a01, b1, acc11, 0, 0, 0);
        b0 = *(const short8*)(sBp + 2560 + offB0);
        b1 = *(const short8*)(sBp + 2560 + offB1);
        acc00 = __builtin_amdgcn_mfma_f32_16x16x32_bf16(a10, b0, acc00, 0, 0, 0);
        acc01 = __builtin_amdgcn_mfma_f32_16x16x32_bf16(a10, b1, acc01, 0, 0, 0);
        acc10 = __builtin_amdgcn_mfma_f32_16x16x32_bf16(a11, b0, acc10, 0, 0, 0);
        acc11 = __builtin_amdgcn_mfma_f32_16x16x32_bf16(a11, b1, acc11, 0, 0, 0);
    };

    ushort8 C0a, C1a, C2a, C3a, C0b, C1b, C2b, C3b;
    float4 Wta, Wtb;
    loadP(0, C0a, C1a, C2a, C3a, Wta);
    loadP(1, C0b, C1b, C2b, C3b, Wtb);
    for (int jh = 0; jh < 9; jh++){
        bodyP(jh * 2,     C0a, C1a, C2a, C3a, Wta);
        bodyP(jh * 2 + 1, C0b, C1b, C2b, C3b, Wtb);
    }

    __syncthreads();
    float* ls = (float*)smem;   // [128][67] fp32 = 34304 B (overlaps tiles; done with them)
    int sp0 = h * 64;
    #pragma unroll
    for (int to = 0; to < 2; to++){
        #pragma unroll
        for (int tn = 0; tn < 2; tn++){
            f32x4 a = to ? (tn ? acc11 : acc10) : (tn ? acc01 : acc00);
            int nl = ng * 32 + tn * 16 + l16;
            #pragma unroll
            for (int r = 0; r < 4; r++){
                int oc = ocq * 32 + to * 16 + quad * 4 + r;
                float v = a[r] + b_reg[oc];
                ybf[(size_t)(b * 128 + oc) * HWi + sp0 + nl] = f2bf(v);
                ls[oc * 67 + nl] = v;
            }
        }
    }
    __syncthreads();
    if (tid < 128){
        int oc = tid;
        float s = 0.f, s2 = 0.f;
        #pragma unroll 8
        for (int nl = 0; nl < 64; nl++){
            float v = ls[oc * 67 + nl];
            s += v; s2 = fmaf(v, v, s2);
        }
        atomicAdd(&psum[oc], s);
        atomicAdd(&psum[128 + oc], s2);
    }
}

// ---------- k_apply: BN (stats inline from psum) + affine + relu -> fp32 ----------
__global__ void k_apply(const unsigned short* __restrict__ ybf, const float* __restrict__ psum,
                        const float* __restrict__ gamma, const float* __restrict__ beta,
                        float* __restrict__ out){
    int lb = ((int)blockIdx.x & 7) * 256 + ((int)blockIdx.x >> 3);
    int e8 = (lb * 256 + (int)threadIdx.x) * 8;
    int c = (e8 >> 12) & 127;
    ushort8 u = *(const ushort8*)(ybf + e8);
    float s = psum[c], s2 = psum[128 + c];
    float mean = s * (1.f / 32768.f);
    float var  = s2 * (1.f / 32768.f) - mean * mean;
    float rs = rsqrtf(var + 1e-5f);
    float g = gamma[c] * rs;
    float bt = beta[c] - mean * g;
    float4 lo, hi;
    lo.x = fmaxf(fmaf(bf2f(u[0]), g, bt), 0.f);
    lo.y = fmaxf(fmaf(bf2f(u[1]), g, bt), 0.f);
    lo.z = fmaxf(fmaf(bf2f(u[2]), g, bt), 0.f);
    lo.w = fmaxf(fmaf(bf2f(u[3]), g, bt), 0.f);
    hi.x = fmaxf(fmaf(bf2f(u[4]), g, bt), 0.f);
    hi.y = fmaxf(fmaf(bf2f(u[5]), g, bt), 0.f);
    hi.z = fmaxf(fmaf(bf2f(u[6]), g, bt), 0.f);
    hi.w = fmaxf(fmaf(bf2f(u[7]), g, bt), 0.f);
    *(float4*)(out + e8)     = lo;
    *(float4*)(out + e8 + 4) = hi;
}

extern "C" void kernel_launch(void* const* d_in, const int* in_sizes, int n_in,
                              void* d_out, int out_size, void* d_ws, size_t ws_size,
                              hipStream_t stream){
    const float* x     = (const float*)d_in[0];
    const float* w_off = (const float*)d_in[1];
    const float* b_off = (const float*)d_in[2];
    const float* w_mod = (const float*)d_in[3];
    const float* b_mod = (const float*)d_in[4];
    const float* w_reg = (const float*)d_in[5];
    const float* b_reg = (const float*)d_in[6];
    const float* gamma = (const float*)d_in[7];
    const float* beta  = (const float*)d_in[8];

    char* wsb = (char*)d_ws;
    unsigned short* xTp   = (unsigned short*)(wsb);                    // 8,921,088 B
    unsigned short* ybf   = (unsigned short*)(wsb + 11018240);         // 8,388,608 B
    unsigned short* wAv   = (unsigned short*)(wsb + 19406848);         //   294,912 B
    unsigned short* w27A  = (unsigned short*)(wsb + 19701760);         //    73,728 B
    float*          biasom= (float*)(wsb + 19775488);                  //       128 B
    float*          psum  = (float*)(wsb + 19775616);                  //     1,024 B
    float* out = (float*)d_out;

    hipLaunchKernelGGL(k_pre,   dim3(1250), dim3(256), 0, stream, x, xTp, w_reg, w_off, w_mod, b_off, b_mod, wAv, w27A, biasom, psum);
    hipLaunchKernelGGL(k_fused, dim3(512),  dim3(512), 0, stream, xTp, w27A, biasom, wAv, b_reg, ybf, psum);
    hipLaunchKernelGGL(k_apply, dim3(2048), dim3(256), 0, stream, ybf, psum, gamma, beta, out);
}